// Round 11
// baseline (36.863 us; speedup 1.0000x reference)
//
#include <hip/hip_runtime.h>

#define NCLUSTER 512
#define NC 3
#define HW 65536
#define BLOCK 512
#define NW 8                     // waves per block = cluster subsets
#define KSUB (NCLUSTER / NW)     // 64 clusters per wave
#define PPT 8                    // pixels per thread (512 px per block)
#define NPAIR (PPT / 2)
#define EPS 1e-4f                // >> 2*delta (delta <= ~3e-5 for |t|<=~100)

typedef float f32x2 __attribute__((ext_vector_type(2)));

// Certified-exact fp32 path: argmin_k d_k == argmin_k t_k,
// t_k = 0.5*||C_k||^2 - x.C_k; exact top-2 certifies when gap >= EPS;
// near-ties queue-compacted, resolved exactly in fp64 (absmax 0 since R8).
// R11: (1) BLOCK=512/NW=8/PPT=8 — each cluster ds_read now feeds 512 px,
// halving per-CU LDS traffic vs R8 at the SAME 16 waves/CU occupancy;
// (2) v_pk_fma_f32 (VOP3P packed fp32, op_sel-broadcast of cluster scalars
// from the {c0,c1}/{c2,w} LDS pairs) computes 2 pixels/instr -> fma issue
// halves. x is pre-negated so no neg modifiers are needed in the asm.
__global__ __launch_bounds__(BLOCK, 4) void kmeans_assign(
    const float* __restrict__ x,   // [4,3,256,256]
    const float* __restrict__ C,   // [512,3]
    int* __restrict__ out)         // [4,65536]
{
    __shared__ f32x2 lcA[NCLUSTER];    // {c0,c1}                  4 KB
    __shared__ f32x2 lcB[NCLUSTER];    // {c2, 0.5*||c||^2}        4 KB
    __shared__ float rb1[NW][BLOCK];   // per-subset best1        16 KB
    __shared__ float rb2[NW][BLOCK];   // per-subset 2nd-best     16 KB
    __shared__ int   ridx[NW][BLOCK];  // per-subset argmin       16 KB
    __shared__ int   qpx[BLOCK];       // near-tie queue           2 KB
    __shared__ int   qcnt;

    if (threadIdx.x == 0) qcnt = 0;
    for (int k = threadIdx.x; k < NCLUSTER; k += BLOCK) {
        double c0 = C[k * NC + 0];
        double c1 = C[k * NC + 1];
        double c2 = C[k * NC + 2];
        lcA[k] = (f32x2){(float)c0, (float)c1};
        lcB[k] = (f32x2){(float)c2, (float)(0.5 * (c0 * c0 + c1 * c1 + c2 * c2))};
    }
    __syncthreads();

    const int w = threadIdx.x >> 6;        // wave id = cluster subset
    const int l = threadIdx.x & 63;        // lane
    const int B0 = blockIdx.x * BLOCK;     // first global pixel of block
    const int pB = B0 & (HW - 1);          // pixel base within batch
    const float* xb = x + (size_t)(B0 >> 16) * NC * HW;

    // Pair j holds pixels (l+128j, l+128j+64) = thread-px (2j, 2j+1), negated.
    f32x2 NX0[NPAIR], NX1[NPAIR], NX2[NPAIR];
    float b1[PPT], b2[PPT];
    int id[PPT];
#pragma unroll
    for (int j = 0; j < NPAIR; ++j) {
        int pa = pB + l + j * 128;
        int pc = pa + 64;
        NX0[j] = (f32x2){-xb[pa], -xb[pc]};
        NX1[j] = (f32x2){-xb[pa + HW], -xb[pc + HW]};
        NX2[j] = (f32x2){-xb[pa + 2 * HW], -xb[pc + 2 * HW]};
    }
#pragma unroll
    for (int i = 0; i < PPT; ++i) { b1[i] = 1e30f; b2[i] = 1e30f; id[i] = 0; }

    const int k0 = w * KSUB;
#pragma unroll 2
    for (int k = 0; k < KSUB; ++k) {
        f32x2 cA = lcA[k0 + k];   // uniform ds_read_b64 {c0,c1}
        f32x2 cB = lcB[k0 + k];   // uniform ds_read_b64 {c2,w}
        const int kk = k0 + k;
#pragma unroll
        for (int j = 0; j < NPAIR; ++j) {
            f32x2 T;
            // T = {fma(nx0.lo,c0,w), fma(nx0.hi,c0,w)}   (B=lo bcast, C=hi bcast)
            asm("v_pk_fma_f32 %0, %1, %2, %3 op_sel:[0,0,1] op_sel_hi:[1,0,1]"
                : "=v"(T) : "v"(NX0[j]), "v"(cA), "v"(cB));
            // T += nx1 * c1                               (B=hi bcast)
            asm("v_pk_fma_f32 %0, %1, %2, %0 op_sel:[0,1,0] op_sel_hi:[1,1,1]"
                : "+v"(T) : "v"(NX1[j]), "v"(cA));
            // T += nx2 * c2                               (B=lo bcast)
            asm("v_pk_fma_f32 %0, %1, %2, %0 op_sel:[0,0,0] op_sel_hi:[1,0,1]"
                : "+v"(T) : "v"(NX2[j]), "v"(cB));
            float t0 = T.x, t1 = T.y;
            {
                const int i = 2 * j;
                bool lt = t0 < b1[i];                              // strict: first k wins
                b2[i] = __builtin_amdgcn_fmed3f(t0, b1[i], b2[i]); // exact 2nd-best
                id[i] = lt ? kk : id[i];
                b1[i] = fminf(t0, b1[i]);
            }
            {
                const int i = 2 * j + 1;
                bool lt = t1 < b1[i];
                b2[i] = __builtin_amdgcn_fmed3f(t1, b1[i], b2[i]);
                id[i] = lt ? kk : id[i];
                b1[i] = fminf(t1, b1[i]);
            }
        }
    }

#pragma unroll
    for (int i = 0; i < PPT; ++i) {
        rb1[w][l + i * 64] = b1[i];
        rb2[w][l + i * 64] = b2[i];
        ridx[w][l + i * 64] = id[i];
    }
    __syncthreads();

    // Merge subsets for pixel t (one px per thread), w ascending so the
    // lowest cluster index wins on equal fp32 scores (argmin semantics).
    {
        const int t = threadIdx.x;
        float g1m = rb1[0][t];
        float g2m = rb2[0][t];
        int gi = ridx[0][t];
#pragma unroll
        for (int ww = 1; ww < NW; ++ww) {
            float a1 = rb1[ww][t];
            float a2 = rb2[ww][t];
            int ai = ridx[ww][t];
            bool lt = a1 < g1m;
            g2m = lt ? fminf(g1m, a2) : fminf(g2m, a1);   // exact global 2nd-best
            gi = lt ? ai : gi;
            g1m = fminf(g1m, a1);
        }
        if (g2m - g1m < EPS) {
            qpx[atomicAdd(&qcnt, 1)] = t;   // near-tie: defer to exact resolve
        } else {
            out[B0 + t] = gi;               // certified correct
        }
    }
    __syncthreads();

    // Wave-cooperative exact resolve: one queued pixel per wave at a time,
    // 64 lanes x 8 clusters, exact fp64 direct distances (validated absmax 0),
    // smallest-k tie-break.
    const int n = qcnt;
    for (int e = w; e < n; e += NW) {
        const int t = qpx[e];
        const int p = pB + t;
        double X0 = (double)xb[p];
        double X1 = (double)xb[p + HW];
        double X2 = (double)xb[p + 2 * HW];
        double bd = 1e300;
        int bi = 0;
#pragma unroll
        for (int j = 0; j < NCLUSTER / 64; ++j) {
            int k = j * 64 + l;              // ascending per lane
            f32x2 a = lcA[k];
            f32x2 b = lcB[k];
            double d0 = X0 - (double)a.x;
            double d1 = X1 - (double)a.y;
            double d2 = X2 - (double)b.x;
            double d = d0 * d0 + d1 * d1 + d2 * d2;
            if (d < bd) { bd = d; bi = k; }  // strict: smallest k in lane wins
        }
#pragma unroll
        for (int m = 1; m < 64; m <<= 1) {   // butterfly argmin reduce
            double od = __shfl_xor(bd, m, 64);
            int oi = __shfl_xor(bi, m, 64);
            bool take = (od < bd) || (od == bd && oi < bi);
            bd = take ? od : bd;
            bi = take ? oi : bi;
        }
        if (l == 0) out[B0 + t] = bi;
    }
}

extern "C" void kernel_launch(void* const* d_in, const int* in_sizes, int n_in,
                              void* d_out, int out_size, void* d_ws, size_t ws_size,
                              hipStream_t stream) {
    const float* x = (const float*)d_in[0];
    const float* C = (const float*)d_in[1];
    int* out = (int*)d_out;

    int total = out_size;              // 262144
    int grid = total / BLOCK;          // 512 blocks -> 2/CU -> 16 waves/CU
    kmeans_assign<<<grid, BLOCK, 0, stream>>>(x, C, out);
}

// Round 12
// 32.403 us; speedup vs baseline: 1.1376x; 1.1376x over previous
//
#include <hip/hip_runtime.h>

#define NCLUSTER 512
#define NC 3
#define HW 65536
#define BLOCK 512                // 8 waves
#define NW 8                     // waves per block = cluster subsets
#define KSUB (NCLUSTER / NW)     // 64 clusters per wave
#define PPT 4                    // pixels per thread (per wave: 64*4 = 256 px)
#define PXB 256                  // pixels per block (all waves share them)
#define EPS 1e-4f                // >> 2*delta (delta <= ~3e-5 for |t|<=~100)

// Certified-exact fp32 path: argmin_k d_k == argmin_k t_k,
// t_k = 0.5*||C_k||^2 - x.C_k; exact global top-2 certifies the fp32 argmin
// when gap >= EPS; near-ties queue-compacted and resolved exactly in fp64
// (absmax 0 in R1/R8-R11). R12: the untested corner of the config grid —
// 8 waves/SIMD (HW max, 4 blocks/CU) AND PPT=4 (balanced LDS/VALU pipes):
// NW=8 cluster-split so each wave scans only 64 clusters for the block's
// 256 pixels. R9(readlane)/R11(pk_fma) proved instruction count is not
// binding; R8 vs R10 isolated the bottleneck to issue stalls that only
// wave-interleave fills. LDS model 10.2 us, VALU 12 us, 32 waves/CU to hide.
__global__ __launch_bounds__(BLOCK, 8) void kmeans_assign(
    const float* __restrict__ x,   // [4,3,256,256]
    const float* __restrict__ C,   // [512,3]
    int* __restrict__ out)         // [4,65536]
{
    __shared__ float4 lc[NCLUSTER];     // {c0,c1,c2, 0.5*||c||^2}  8 KB
    __shared__ float  rb1[NW][PXB];     // per-subset best1          8 KB
    __shared__ float  rb2[NW][PXB];     // per-subset exact 2nd-best 8 KB
    __shared__ int    ridx[NW][PXB];    // per-subset argmin         8 KB
    __shared__ int    qpx[PXB];         // near-tie pixel queue      1 KB
    __shared__ int    qcnt;

    const int w = threadIdx.x >> 6;        // wave id = cluster subset
    const int l = threadIdx.x & 63;        // lane
    const int B0 = blockIdx.x * PXB;       // first global pixel of block
    const int pB = B0 & (HW - 1);          // pixel base within batch
    const float* xb = x + (size_t)(B0 >> 16) * NC * HW;

    // Issue x loads first: global latency overlaps the LDS staging below.
    float x0[PPT], x1[PPT], x2[PPT];
#pragma unroll
    for (int i = 0; i < PPT; ++i) {
        int p = pB + l + i * 64;
        x0[i] = xb[p];
        x1[i] = xb[p + HW];
        x2[i] = xb[p + 2 * HW];
    }

    if (threadIdx.x == 0) qcnt = 0;
    {   // 512 threads stage 512 clusters in one sweep
        int k = threadIdx.x;
        double c0 = C[k * NC + 0];
        double c1 = C[k * NC + 1];
        double c2 = C[k * NC + 2];
        lc[k] = make_float4((float)c0, (float)c1, (float)c2,
                            (float)(0.5 * (c0 * c0 + c1 * c1 + c2 * c2)));
    }
    __syncthreads();

    float b1[PPT], b2[PPT];
    int id[PPT];
#pragma unroll
    for (int i = 0; i < PPT; ++i) { b1[i] = 1e30f; b2[i] = 1e30f; id[i] = 0; }

    const int k0 = w * KSUB;
#pragma unroll 4
    for (int k = 0; k < KSUB; ++k) {
        float4 c = lc[k0 + k];   // one uniform ds_read_b128, 28 VALU ops follow
#pragma unroll
        for (int i = 0; i < PPT; ++i) {
            float t = __builtin_fmaf(-x0[i], c.x, c.w);
            t = __builtin_fmaf(-x1[i], c.y, t);
            t = __builtin_fmaf(-x2[i], c.z, t);
            bool lt = t < b1[i];                              // strict: first k wins
            b2[i] = __builtin_amdgcn_fmed3f(t, b1[i], b2[i]); // exact 2nd-best
            id[i] = lt ? (k0 + k) : id[i];
            b1[i] = fminf(t, b1[i]);
        }
    }

#pragma unroll
    for (int i = 0; i < PPT; ++i) {
        rb1[w][l + i * 64] = b1[i];
        rb2[w][l + i * 64] = b2[i];
        ridx[w][l + i * 64] = id[i];
    }
    __syncthreads();

    // Merge subsets for pixel t (threads 0..PXB-1), w ascending so the
    // lowest cluster index wins on equal fp32 scores (argmin semantics).
    if (threadIdx.x < PXB) {
        const int t = threadIdx.x;
        float g1m = rb1[0][t];
        float g2m = rb2[0][t];
        int gi = ridx[0][t];
#pragma unroll
        for (int ww = 1; ww < NW; ++ww) {
            float a1 = rb1[ww][t];
            float a2 = rb2[ww][t];
            int ai = ridx[ww][t];
            bool lt = a1 < g1m;
            g2m = lt ? fminf(g1m, a2) : fminf(g2m, a1);   // exact global 2nd-best
            gi = lt ? ai : gi;
            g1m = fminf(g1m, a1);
        }
        if (g2m - g1m < EPS) {
            qpx[atomicAdd(&qcnt, 1)] = t;   // near-tie: defer to exact resolve
        } else {
            out[B0 + t] = gi;               // certified correct
        }
    }
    __syncthreads();

    // Wave-cooperative exact resolve: one queued pixel per wave at a time,
    // 64 lanes x 8 clusters, exact fp64 direct distances (validated absmax 0),
    // smallest-k tie-break.
    const int n = qcnt;
    for (int e = w; e < n; e += NW) {
        const int t = qpx[e];
        const int p = pB + t;
        double X0 = (double)xb[p];
        double X1 = (double)xb[p + HW];
        double X2 = (double)xb[p + 2 * HW];
        double bd = 1e300;
        int bi = 0;
#pragma unroll
        for (int j = 0; j < NCLUSTER / 64; ++j) {
            int k = j * 64 + l;              // ascending per lane
            float4 c = lc[k];
            double d0 = X0 - (double)c.x;
            double d1 = X1 - (double)c.y;
            double d2 = X2 - (double)c.z;
            double d = d0 * d0 + d1 * d1 + d2 * d2;
            if (d < bd) { bd = d; bi = k; }  // strict: smallest k in lane wins
        }
#pragma unroll
        for (int m = 1; m < 64; m <<= 1) {   // butterfly argmin reduce
            double od = __shfl_xor(bd, m, 64);
            int oi = __shfl_xor(bi, m, 64);
            bool take = (od < bd) || (od == bd && oi < bi);
            bd = take ? od : bd;
            bi = take ? oi : bi;
        }
        if (l == 0) out[B0 + t] = bi;
    }
}

extern "C" void kernel_launch(void* const* d_in, const int* in_sizes, int n_in,
                              void* d_out, int out_size, void* d_ws, size_t ws_size,
                              hipStream_t stream) {
    const float* x = (const float*)d_in[0];
    const float* C = (const float*)d_in[1];
    int* out = (int*)d_out;

    int total = out_size;              // 262144
    int grid = total / PXB;            // 1024 blocks -> 4/CU -> 32 waves/CU
    kmeans_assign<<<grid, BLOCK, 0, stream>>>(x, C, out);
}